// Round 13
// baseline (74.722 us; speedup 1.0000x reference)
//
#include <hip/hip_runtime.h>

#define HW 4096
#define NC 256
#define NP 8
#define NB 32
#define SUBHW 32           // hw per pipeline stage
#define NSUB 8             // stages per block
#define SPAN 256           // hw per block
#define NSP 16             // spans per batch
#define NBLK (NB * NSP)    // 512 blocks

#define FMA4(acc, v, s)                  \
  acc.x = fmaf((v).x, (s), acc.x);       \
  acc.y = fmaf((v).y, (s), acc.y);       \
  acc.z = fmaf((v).z, (s), acc.z);       \
  acc.w = fmaf((v).w, (s), acc.w)

// A2: consume xv[8] -> scores s4, stage swizzled xs[bf], reduce -> sp.
// One load instr = 8 complete 128B rows (row = 32 floats = SUBHW).
// Swizzle slot = q ^ (c&7): write instr hits each bank-quad exactly 8x
// (= data minimum); B-side row-read same property. c&7 == cr here.
#define PHASE_A2(bf)                                               \
  {                                                                \
    float4 s4[NP];                                                 \
    _Pragma("unroll")                                              \
    for (int p = 0; p < NP; ++p) s4[p] = make_float4(0.f, 0.f, 0.f, 0.f); \
    _Pragma("unroll")                                              \
    for (int i = 0; i < 8; ++i) {                                  \
      int c = c0 + i * 8 + cr;                                     \
      float4 wA = *(const float4*)&wt[c][0];                       \
      float4 wB = *(const float4*)&wt[c][4];                       \
      FMA4(s4[0], xv[i], wA.x);                                    \
      FMA4(s4[1], xv[i], wA.y);                                    \
      FMA4(s4[2], xv[i], wA.z);                                    \
      FMA4(s4[3], xv[i], wA.w);                                    \
      FMA4(s4[4], xv[i], wB.x);                                    \
      FMA4(s4[5], xv[i], wB.y);                                    \
      FMA4(s4[6], xv[i], wB.z);                                    \
      FMA4(s4[7], xv[i], wB.w);                                    \
    }                                                              \
    _Pragma("unroll")                                              \
    for (int i = 0; i < 8; ++i) {                                  \
      int c = c0 + i * 8 + cr;                                     \
      *(float4*)&xs[bf][c][(q ^ cr) * 4] = xv[i];                  \
    }                                                              \
    _Pragma("unroll")                                              \
    for (int p = 0; p < NP; ++p) {                                 \
      float4 v = s4[p];                                            \
      v.x += __shfl_xor(v.x, 8);  v.y += __shfl_xor(v.y, 8);       \
      v.z += __shfl_xor(v.z, 8);  v.w += __shfl_xor(v.w, 8);       \
      v.x += __shfl_xor(v.x, 16); v.y += __shfl_xor(v.y, 16);      \
      v.z += __shfl_xor(v.z, 16); v.w += __shfl_xor(v.w, 16);      \
      v.x += __shfl_xor(v.x, 32); v.y += __shfl_xor(v.y, 32);      \
      v.z += __shfl_xor(v.z, 32); v.w += __shfl_xor(v.w, 32);      \
      if (cr == 0) *(float4*)&sp[w][p][q * 4] = v;                 \
    }                                                              \
  }

// ---------------- Fused pipelined: per (b, 256-hw span) block ----------------
// Loop over 8 sub-chunks of 32 hw with double-buffered xs:
//   e(k) -> barrier -> A-loads(k+1) issue; B(k) runs under the load latency;
//   A-FMA+stage(k+1) -> barrier.  HBM pipe stays fed every iteration
//   (fixes R12's phase-serialization at 2 blocks/CU).
// e = exp(score+bias); no max-subtract (|s|<~5; ratios identical; absmax
// ~1e-7 validated R1-R12). Loop NOT unrolled (R11: unroll+held regs = spill).
__global__ __launch_bounds__(256) void k_fused(
    const float* __restrict__ x, const float* __restrict__ Wm,
    const float* __restrict__ bias, float* __restrict__ partial,
    float* __restrict__ psum) {
  __shared__ __align__(16) float xs[2][NC][SUBHW];  // 64 KB double-buffered tile
  __shared__ __align__(16) float wt[NC][NP];        // 8 KB W^T (persistent)
  __shared__ __align__(16) float sp[4][NP][SUBHW];  // 4 KB score partials
  __shared__ __align__(16) float els[2][NP][SUBHW]; // 2 KB e double-buffered

  const int bid = blockIdx.x;
  const int b = bid >> 4;
  const int span = bid & 15;
  const int t = threadIdx.x, lane = t & 63, w = t >> 6;
  const float* xb = x + (size_t)b * NC * HW + span * SPAN;

  const int cr = lane >> 3;   // row-in-group 0..7
  const int q = lane & 7;     // float4 seg within 32-float row
  const int c0 = w << 6;
  const int ep = t >> 5, eh = t & 31;
  const float* xwp = xb + (size_t)(c0 + cr) * HW + q * 4;

  // ---- A1(0): issue loads before the staging barrier ----
  float4 xv[8];
#pragma unroll
  for (int i = 0; i < 8; ++i)
    xv[i] = *(const float4*)(xwp + (size_t)(i * 8) * HW);

  // ---- stage W^T (once) ----
#pragma unroll
  for (int p = 0; p < NP; ++p) wt[t][p] = Wm[p * NC + t];
  __syncthreads();

  const float bia = bias[ep];
  float acc[NP];
#pragma unroll
  for (int p = 0; p < NP; ++p) acc[p] = 0.f;
  float esum_tot = 0.f;

  // ---- A2(0) ----
  PHASE_A2(0)
  __syncthreads();

#pragma unroll 1
  for (int k = 0; k < NSUB; ++k) {
    const int bf = k & 1;

    // ---- e(k): score -> exp -> els[bf]; esum accumulated (no shuffles here) ----
    {
      float a = bia;
#pragma unroll
      for (int ww = 0; ww < 4; ++ww) a += sp[ww][ep][eh];
      float e0 = expf(a);
      els[bf][ep][eh] = e0;
      esum_tot += e0;
    }
    __syncthreads();  // sp free for A2(k+1); els[bf] visible for B(k)

    if (k + 1 < NSUB) {
      // ---- A1(k+1): issue loads; latency hides under B(k) ----
      const float* xn = xwp + (k + 1) * SUBHW;
#pragma unroll
      for (int i = 0; i < 8; ++i)
        xv[i] = *(const float4*)(xn + (size_t)(i * 8) * HW);
    }

    // ---- B(k): thread = row c = t; swizzled LDS reads; els broadcast ----
    {
      const int tk = t & 7;
#pragma unroll
      for (int j = 0; j < 8; ++j) {
        float4 xvb = *(const float4*)&xs[bf][t][(j ^ tk) * 4];
#pragma unroll
        for (int p = 0; p < NP; ++p) {
          float4 e4 = *(const float4*)&els[bf][p][j * 4];  // uniform -> broadcast
          acc[p] = fmaf(xvb.x, e4.x, acc[p]);
          acc[p] = fmaf(xvb.y, e4.y, acc[p]);
          acc[p] = fmaf(xvb.z, e4.z, acc[p]);
          acc[p] = fmaf(xvb.w, e4.w, acc[p]);
        }
      }
    }

    if (k + 1 < NSUB) {
      // ---- A2(k+1): consume xv -> s4 -> stage xs[bf^1] -> sp ----
      PHASE_A2(bf ^ 1)
    }
    __syncthreads();  // xs[bf^1] + sp visible for next iteration
  }

  // ---- epilogue: coalesced partial write + one-time esum reduce ----
#pragma unroll
  for (int p = 0; p < NP; ++p)
    partial[((size_t)bid * NP + p) * NC + t] = acc[p];

#pragma unroll
  for (int off = 16; off; off >>= 1) esum_tot += __shfl_xor(esum_tot, off);
  if (eh == 0) psum[bid * NP + ep] = esum_tot;
}

// ---------------- Reduce: out[b,p,c] = ginv * sum_span partial ----------------
__global__ __launch_bounds__(256) void k_reduce(
    const float* __restrict__ partial, const float* __restrict__ psum,
    float* __restrict__ out) {
  int bp = blockIdx.x;  // b*8 + p
  int b = bp >> 3, p = bp & 7;
  int t = threadIdx.x, lane = t & 63, w2 = t >> 6;

  __shared__ float gv;
  if (w2 == 0) {
    float v = (lane < NSP) ? psum[(size_t)(b * NSP + lane) * NP + p] : 0.f;
#pragma unroll
    for (int off = 8; off; off >>= 1) v += __shfl_xor(v, off);
    if (lane == 0) gv = 1.0f / (v * (float)HW);
  }
  __syncthreads();
  float ginv = gv;

  float acc = 0.f;
#pragma unroll
  for (int i = 0; i < NSP; ++i)
    acc += partial[(((size_t)b * NSP + i) * NP + p) * NC + t];
  out[((size_t)b * NP + p) * NC + t] = acc * ginv;
}

extern "C" void kernel_launch(void* const* d_in, const int* in_sizes, int n_in,
                              void* d_out, int out_size, void* d_ws, size_t ws_size,
                              hipStream_t stream) {
  const float* x = (const float*)d_in[0];
  const float* Wm = (const float*)d_in[1];
  const float* bias = (const float*)d_in[2];
  float* out = (float*)d_out;

  float* ws = (float*)d_ws;
  float* partial = ws;                              // 512*8*256 floats = 4 MiB
  float* psum = ws + (size_t)NBLK * NP * NC;        // 512*8 floats

  k_fused<<<NBLK, 256, 0, stream>>>(x, Wm, bias, partial, psum);
  k_reduce<<<NB * NP, 256, 0, stream>>>(partial, psum, out);
}

// Round 14
// 71.644 us; speedup vs baseline: 1.0430x; 1.0430x over previous
//
#include <hip/hip_runtime.h>

#define HW 4096
#define NC 256
#define NP 8
#define NB 32
#define SUBHW 32          // hw per chunk
#define SPAN 64           // hw per block (2 chunks)
#define NSP 64            // spans per batch
#define NBLK (NB * NSP)   // 2048 blocks

#define FMA4(acc, v, s)                  \
  acc.x = fmaf((v).x, (s), acc.x);       \
  acc.y = fmaf((v).y, (s), acc.y);       \
  acc.z = fmaf((v).z, (s), acc.z);       \
  acc.w = fmaf((v).w, (s), acc.w)

// ---------------- Fused: x register-resident, distributed pool accumulator ----------------
// Per (b, 64-hw span) block; 2 chunks of 32 hw. Lane = (cr in 0..7, q in 0..7):
// holds rows c = 64w + 8i + cr (i<8), hw segment q*4. Per chunk:
//   A: 8 b128 loads -> xv[8] (32 VGPR); scores s4[p] += xv*wt (LDS W^T, 2-way
//      alias = free); ONE cr-reduce (xor 8,16,32) -> sp; barrier.
//   e: exp(bias + sum_w sp) -> els; barrier.  (no max-subtract: |s|<~5,
//      ratios identical; absmax ~1e-7 validated R1-R13)
//   pool: acc[i][p] += dot4(xv[i], els-bcast) -- NO per-chunk cross-lane
//      reduction (R7 lesson); acc q-reduced ONCE at epilogue.
// x read from HBM exactly once, never staged to LDS (R12's 64KB tile + its
// write/read round-trip eliminated). LDS 13 KB; launch_bounds(256,3) caps
// VGPR ~170 (R5/R11/R13: unbounded fat bodies spill).
__global__ __launch_bounds__(256, 3) void k_fused(
    const float* __restrict__ x, const float* __restrict__ Wm,
    const float* __restrict__ bias, float* __restrict__ partial,
    float* __restrict__ psum) {
  __shared__ __align__(16) float wt[NC][NP];        // 8 KB W^T
  __shared__ __align__(16) float sp[4][NP][SUBHW];  // 4 KB score partials
  __shared__ __align__(16) float els[NP][SUBHW];    // 1 KB e values

  const int bid = blockIdx.x;
  const int b = bid >> 6;
  const int span = bid & 63;
  const int t = threadIdx.x, lane = t & 63, w = t >> 6;
  const int cr = lane >> 3;   // row-in-group 0..7
  const int q = lane & 7;     // 16B seg 0..7
  const int c0 = w << 6;
  const int ep = t >> 5, eh = t & 31;

  // ---- stage W^T (once) ----
#pragma unroll
  for (int p = 0; p < NP; ++p) wt[t][p] = Wm[p * NC + t];

  const float* xq = x + (size_t)b * NC * HW + span * SPAN + q * 4;
  const float bia = bias[ep];

  float acc[8][NP];
#pragma unroll
  for (int i = 0; i < 8; ++i)
#pragma unroll
    for (int p = 0; p < NP; ++p) acc[i][p] = 0.f;
  float esum_tot = 0.f;

  __syncthreads();  // wt ready

#pragma unroll 1
  for (int k = 0; k < 2; ++k) {
    // ---- A: 8 back-to-back b128 loads (8 rows x 128B per instr) ----
    float4 xv[8];
#pragma unroll
    for (int i = 0; i < 8; ++i)
      xv[i] = *(const float4*)(xq + k * SUBHW + (size_t)(c0 + 8 * i + cr) * HW);

    float4 s4[NP];
#pragma unroll
    for (int p = 0; p < NP; ++p) s4[p] = make_float4(0.f, 0.f, 0.f, 0.f);
#pragma unroll
    for (int i = 0; i < 8; ++i) {
      const float4 wA = *(const float4*)&wt[c0 + 8 * i + cr][0];  // 2-way alias: free
      const float4 wB = *(const float4*)&wt[c0 + 8 * i + cr][4];
      FMA4(s4[0], xv[i], wA.x);
      FMA4(s4[1], xv[i], wA.y);
      FMA4(s4[2], xv[i], wA.z);
      FMA4(s4[3], xv[i], wA.w);
      FMA4(s4[4], xv[i], wB.x);
      FMA4(s4[5], xv[i], wB.y);
      FMA4(s4[6], xv[i], wB.z);
      FMA4(s4[7], xv[i], wB.w);
    }

    // ---- cr-reduce once (lane bits 3,4,5); cr==0 lanes -> sp ----
#pragma unroll
    for (int p = 0; p < NP; ++p) {
      float4 v = s4[p];
      v.x += __shfl_xor(v.x, 8);  v.y += __shfl_xor(v.y, 8);
      v.z += __shfl_xor(v.z, 8);  v.w += __shfl_xor(v.w, 8);
      v.x += __shfl_xor(v.x, 16); v.y += __shfl_xor(v.y, 16);
      v.z += __shfl_xor(v.z, 16); v.w += __shfl_xor(v.w, 16);
      v.x += __shfl_xor(v.x, 32); v.y += __shfl_xor(v.y, 32);
      v.z += __shfl_xor(v.z, 32); v.w += __shfl_xor(v.w, 32);
      if (cr == 0) *(float4*)&sp[w][p][q * 4] = v;
    }
    __syncthreads();

    // ---- e = exp(score + bias) -> els; esum accumulated ----
    {
      float a = bia;
#pragma unroll
      for (int ww = 0; ww < 4; ++ww) a += sp[ww][ep][eh];
      float e0 = expf(a);
      els[ep][eh] = e0;
      esum_tot += e0;
    }
    __syncthreads();

    // ---- pool: acc[i][p] += dot4(xv[i], e4[p]); zero shuffles ----
#pragma unroll
    for (int p = 0; p < NP; ++p) {
      const float4 e4 = *(const float4*)&els[p][q * 4];  // 8-lane broadcast, conflict-free
#pragma unroll
      for (int i = 0; i < 8; ++i) {
        acc[i][p] = fmaf(xv[i].x, e4.x, acc[i][p]);
        acc[i][p] = fmaf(xv[i].y, e4.y, acc[i][p]);
        acc[i][p] = fmaf(xv[i].z, e4.z, acc[i][p]);
        acc[i][p] = fmaf(xv[i].w, e4.w, acc[i][p]);
      }
    }
  }

  // ---- epilogue: q-reduce acc ONCE (lane bits 0..2); q==0 lanes write ----
#pragma unroll
  for (int i = 0; i < 8; ++i)
#pragma unroll
    for (int p = 0; p < NP; ++p) {
      float v = acc[i][p];
      v += __shfl_xor(v, 1);
      v += __shfl_xor(v, 2);
      v += __shfl_xor(v, 4);
      acc[i][p] = v;
    }
  if (q == 0) {
#pragma unroll
    for (int i = 0; i < 8; ++i) {
      const int c = c0 + 8 * i + cr;
#pragma unroll
      for (int p = 0; p < NP; ++p)
        partial[((size_t)bid * NP + p) * NC + c] = acc[i][p];  // 8 lanes, 8 consecutive dwords
    }
  }

  // ---- psum: esum_tot reduced over the 32 eh-lanes ----
#pragma unroll
  for (int off = 16; off; off >>= 1) esum_tot += __shfl_xor(esum_tot, off);
  if (eh == 0) psum[bid * NP + ep] = esum_tot;
}

// ---------------- Reduce: out[b,p,c] = ginv * sum_span partial ----------------
__global__ __launch_bounds__(256) void k_reduce(
    const float* __restrict__ partial, const float* __restrict__ psum,
    float* __restrict__ out) {
  int bp = blockIdx.x;  // b*8 + p
  int b = bp >> 3, p = bp & 7;
  int t = threadIdx.x, lane = t & 63, w2 = t >> 6;

  __shared__ float gv;
  if (w2 == 0) {
    float v = psum[(size_t)(b * NSP + lane) * NP + p];
#pragma unroll
    for (int off = 32; off; off >>= 1) v += __shfl_xor(v, off);
    if (lane == 0) gv = 1.0f / (v * (float)HW);
  }
  __syncthreads();
  float ginv = gv;

  float acc = 0.f;
#pragma unroll 16
  for (int ch = 0; ch < NSP; ++ch)
    acc += partial[(((size_t)b * NSP + ch) * NP + p) * NC + t];
  out[((size_t)b * NP + p) * NC + t] = acc * ginv;
}

extern "C" void kernel_launch(void* const* d_in, const int* in_sizes, int n_in,
                              void* d_out, int out_size, void* d_ws, size_t ws_size,
                              hipStream_t stream) {
  const float* x = (const float*)d_in[0];
  const float* Wm = (const float*)d_in[1];
  const float* bias = (const float*)d_in[2];
  float* out = (float*)d_out;

  float* ws = (float*)d_ws;
  float* partial = ws;                              // 2048*8*256 floats = 16 MiB
  float* psum = ws + (size_t)NBLK * NP * NC;        // 2048*8 floats

  k_fused<<<NBLK, 256, 0, stream>>>(x, Wm, bias, partial, psum);
  k_reduce<<<NB * NP, 256, 0, stream>>>(partial, psum, out);
}

// Round 15
// 53.298 us; speedup vs baseline: 1.4020x; 1.3442x over previous
//
#include <hip/hip_runtime.h>

#define HW 4096
#define NC 256
#define NP 8
#define NB 32
#define CHW 64
#define NCH 64   // chunks per batch -> grid 2048

#define FMA4(acc, v, s)                  \
  acc.x = fmaf((v).x, (s), acc.x);       \
  acc.y = fmaf((v).y, (s), acc.y);       \
  acc.z = fmaf((v).z, (s), acc.z);       \
  acc.w = fmaf((v).w, (s), acc.w)

// W^T during phase A; els[8][64] after (lifetimes disjoint: wt last read
// before the first barrier, els first written after it).
#define WT(c, pp) wt_els[(c) * NP + (pp)]
#define ELS(pp, hw) wt_els[(pp) * 64 + (hw)]

// ---------------- Fused: per (b, 64-hw chunk) block; grid 2048 ----------------
// R12 winning body with two changes:
//  (1) phase A issues ALL 16 b128 loads in one batch (16 KB/wave in flight;
//      transient registers only — no barrier-crossing state, no loop unroll).
//  (2) epilogue atomicAdds unnormalized pooled values into a 256 KB
//      L2-resident accumulator (kills 16 MB partial write + 16 MB read +
//      the 256-block reduce kernel). fp32 atomic reorder noise ~1e-9 —
//      far below the 6.4e-7 validation threshold.
// Swizzle (validated R12): row c, logical 16B-seg q stored at slot q^(c&7);
// phase-B row-read of seg j fetches slot j^(t&7). Both sides hit each bank
// exactly 8x per b128 instr (= data minimum).
// e = exp(score+bias); no max-subtract (|s|<~5; ratios identical; absmax
// ~1e-7 validated R1-R14). LDS = 64+8+8 = 80 KB -> 2 blocks/CU.
__global__ __launch_bounds__(256) void k_fused(
    const float* __restrict__ x, const float* __restrict__ Wm,
    const float* __restrict__ bias, float* __restrict__ accw,
    float* __restrict__ psum) {
  __shared__ __align__(16) float xs[NC][64];       // 64 KB swizzled x-tile
  __shared__ __align__(16) float sp[4][NP][CHW];   // 8 KB score partials
  __shared__ __align__(16) float wt_els[NC * NP];  // 8 KB (wt, then els)

  const int bid = blockIdx.x;
  const int b = bid >> 6;
  const int chunk = bid & 63;
  const int t = threadIdx.x, lane = t & 63, w = t >> 6;
  const float* xb = x + (size_t)b * NC * HW + chunk * CHW;

  // ---- stage W^T (once) ----
#pragma unroll
  for (int p = 0; p < NP; ++p) WT(t, p) = Wm[p * NC + t];
  __syncthreads();

  // ---- Phase A: scores; wave w -> c in [64w,64w+64) ----
  const int cr = lane >> 4;   // row-in-group 0..3
  const int q = lane & 15;    // 16B-seg index
  const int c0 = w << 6;
  const float* xwp = xb + (size_t)(c0 + cr) * HW + q * 4;

  float4 s4[NP];
#pragma unroll
  for (int p = 0; p < NP; ++p) s4[p] = make_float4(0.f, 0.f, 0.f, 0.f);

  {
    float4 xv[16];
#pragma unroll
    for (int i = 0; i < 16; ++i)   // 16 back-to-back 1KB wave-loads (16 KB in flight)
      xv[i] = *(const float4*)(xwp + (size_t)(i * 4) * HW);

#pragma unroll
    for (int i = 0; i < 16; ++i) { // stage into swizzled LDS tile + score FMAs
      int c = c0 + i * 4 + cr;
      *(float4*)&xs[c][(q ^ (c & 7)) << 2] = xv[i];
      float4 wA = *(const float4*)&WT(c, 0);
      float4 wB = *(const float4*)&WT(c, 4);
      FMA4(s4[0], xv[i], wA.x);
      FMA4(s4[1], xv[i], wA.y);
      FMA4(s4[2], xv[i], wA.z);
      FMA4(s4[3], xv[i], wA.w);
      FMA4(s4[4], xv[i], wB.x);
      FMA4(s4[5], xv[i], wB.y);
      FMA4(s4[6], xv[i], wB.z);
      FMA4(s4[7], xv[i], wB.w);
    }
  }

  // csub-reduce once (lane bits 4,5); cr==0 lanes write sp
#pragma unroll
  for (int p = 0; p < NP; ++p) {
    float4 v = s4[p];
    v.x += __shfl_xor(v.x, 16); v.y += __shfl_xor(v.y, 16);
    v.z += __shfl_xor(v.z, 16); v.w += __shfl_xor(v.w, 16);
    v.x += __shfl_xor(v.x, 32); v.y += __shfl_xor(v.y, 32);
    v.z += __shfl_xor(v.z, 32); v.w += __shfl_xor(v.w, 32);
    if (cr == 0) *(float4*)&sp[w][p][q * 4] = v;
  }
  __syncthreads();   // wt reads done; xs writes visible

  // ---- e = exp(score + bias) -> els (overlays wt); psum partial ----
  {
    const int ep = t >> 5, eh = t & 31;
    float a0 = bias[ep], a1 = a0;
#pragma unroll
    for (int ww = 0; ww < 4; ++ww) {
      a0 += sp[ww][ep][eh];
      a1 += sp[ww][ep][eh + 32];
    }
    float e0 = expf(a0), e1 = expf(a1);
    ELS(ep, eh) = e0;
    ELS(ep, eh + 32) = e1;
    float esum = e0 + e1;
#pragma unroll
    for (int off = 16; off; off >>= 1) esum += __shfl_xor(esum, off);
    if (eh == 0) psum[bid * NP + ep] = esum;
  }
  __syncthreads();

  // ---- Phase B: pool; thread = row c = t; x from swizzled LDS ----
  const int tk = t & 7;
  float acc[NP];
#pragma unroll
  for (int p = 0; p < NP; ++p) acc[p] = 0.f;

#pragma unroll
  for (int h = 0; h < 2; ++h) {
    float4 xv[8];
#pragma unroll
    for (int j = 0; j < 8; ++j) {
      int k = h * 8 + j;
      xv[j] = *(const float4*)&xs[t][(k ^ tk) << 2];  // logical seg k
    }
#pragma unroll
    for (int j = 0; j < 8; ++j) {
      const int k = h * 8 + j;
#pragma unroll
      for (int p = 0; p < NP; ++p) {
        float4 e4 = *(const float4*)&ELS(p, k * 4);   // uniform -> broadcast
        acc[p] = fmaf(xv[j].x, e4.x, acc[p]);
        acc[p] = fmaf(xv[j].y, e4.y, acc[p]);
        acc[p] = fmaf(xv[j].z, e4.z, acc[p]);
        acc[p] = fmaf(xv[j].w, e4.w, acc[p]);
      }
    }
  }

  // ---- epilogue: lane-coalesced atomic accumulate (L2-resident 256 KB) ----
#pragma unroll
  for (int p = 0; p < NP; ++p)
    atomicAdd(&accw[(size_t)b * NP * NC + p * NC + t], acc[p]);
}

// ---------------- Norm: out[b,p,c] = accw[b,p,c] / (esum_b[p] * HW) ----------------
__global__ __launch_bounds__(256) void k_norm(
    const float* __restrict__ accw, const float* __restrict__ psum,
    float* __restrict__ out) {
  __shared__ float gv[NP];
  const int b = blockIdx.x;
  const int t = threadIdx.x, lane = t & 63, w2 = t >> 6;

  if (w2 == 0) {
#pragma unroll
    for (int p = 0; p < NP; ++p) {
      float v = psum[(size_t)(b * NCH + lane) * NP + p];
#pragma unroll
      for (int off = 32; off; off >>= 1) v += __shfl_xor(v, off);
      if (lane == 0) gv[p] = 1.0f / (v * (float)HW);
    }
  }
  __syncthreads();

#pragma unroll
  for (int it = 0; it < NP; ++it) {
    int e = it * 256 + t;          // 0..2047
    int p = e >> 8;
    out[(size_t)b * NP * NC + e] = accw[(size_t)b * NP * NC + e] * gv[p];
  }
}

extern "C" void kernel_launch(void* const* d_in, const int* in_sizes, int n_in,
                              void* d_out, int out_size, void* d_ws, size_t ws_size,
                              hipStream_t stream) {
  const float* x = (const float*)d_in[0];
  const float* Wm = (const float*)d_in[1];
  const float* bias = (const float*)d_in[2];
  float* out = (float*)d_out;

  float* ws = (float*)d_ws;
  float* accw = ws;                                 // 32*8*256 floats = 256 KB
  float* psum = ws + (size_t)NB * NP * NC;          // 2048*8 floats

  hipMemsetAsync(accw, 0, (size_t)NB * NP * NC * sizeof(float), stream);
  k_fused<<<NB * NCH, 256, 0, stream>>>(x, Wm, bias, accw, psum);
  k_norm<<<NB, 256, 0, stream>>>(accw, psum, out);
}